// Round 4
// baseline (1743.366 us; speedup 1.0000x reference)
//
#include <hip/hip_runtime.h>
#include <hip/hip_bf16.h>

typedef __attribute__((ext_vector_type(8))) short short8;   // 8 x bf16
typedef __attribute__((ext_vector_type(4))) float f32x4;

#define MFMA16(a, b, c) __builtin_amdgcn_mfma_f32_16x16x32_bf16(a, b, c, 0, 0, 0)

static __device__ __forceinline__ float gelu_f(float v) {
    return 0.5f * v * (1.0f + erff(v * 0.70710678118654752f));
}

// ---------------- LayerNorm: fp32 x -> bf16 xn (used once, layer-0 ln1) ----------------
__global__ __launch_bounds__(256) void ln_kernel(
    const float* __restrict__ x, const float* __restrict__ g, const float* __restrict__ bb,
    __hip_bfloat16* __restrict__ xn) {
    int row = blockIdx.x;
    const float* xr = x + (size_t)row * 768;
    int tid = threadIdx.x;
    float v0 = xr[tid], v1 = xr[tid + 256], v2 = xr[tid + 512];
    float s = v0 + v1 + v2;
    float s2 = v0 * v0 + v1 * v1 + v2 * v2;
    for (int m = 1; m < 64; m <<= 1) { s += __shfl_xor(s, m); s2 += __shfl_xor(s2, m); }
    __shared__ float ls[4], ls2[4];
    if ((tid & 63) == 0) { ls[tid >> 6] = s; ls2[tid >> 6] = s2; }
    __syncthreads();
    s = ls[0] + ls[1] + ls[2] + ls[3];
    s2 = ls2[0] + ls2[1] + ls2[2] + ls2[3];
    float mean = s * (1.0f / 768.0f);
    float var = s2 * (1.0f / 768.0f) - mean * mean;
    float rstd = rsqrtf(var + 1e-5f);
    __hip_bfloat16* xo = xn + (size_t)row * 768;
    xo[tid]       = __float2bfloat16((v0 - mean) * rstd * g[tid]       + bb[tid]);
    xo[tid + 256] = __float2bfloat16((v1 - mean) * rstd * g[tid + 256] + bb[tid + 256]);
    xo[tid + 512] = __float2bfloat16((v2 - mean) * rstd * g[tid + 512] + bb[tid + 512]);
}

// ---------------- Fused split-K reduce + bias + residual + LayerNorm ----------------
__global__ __launch_bounds__(256) void reduce_ln_kernel(
    const __hip_bfloat16* __restrict__ P, int SK,
    const float* __restrict__ bias, float* __restrict__ x,
    const float* __restrict__ g, const float* __restrict__ bb,
    __hip_bfloat16* __restrict__ xn) {
    const size_t MN = (size_t)4096 * 768;
    int row = blockIdx.x, tid = threadIdx.x;
    float v[3];
    float s = 0.f, s2 = 0.f;
    for (int j = 0; j < 3; j++) {
        int c = tid + j * 256;
        size_t idx = (size_t)row * 768 + c;
        float val = x[idx] + bias[c];
        for (int sk = 0; sk < SK; sk++) val += __bfloat162float(P[(size_t)sk * MN + idx]);
        x[idx] = val;
        v[j] = val;
        s += val; s2 += val * val;
    }
    for (int m = 1; m < 64; m <<= 1) { s += __shfl_xor(s, m); s2 += __shfl_xor(s2, m); }
    __shared__ float ls[4], ls2[4];
    if ((tid & 63) == 0) { ls[tid >> 6] = s; ls2[tid >> 6] = s2; }
    __syncthreads();
    s = ls[0] + ls[1] + ls[2] + ls[3];
    s2 = ls2[0] + ls2[1] + ls2[2] + ls2[3];
    float mean = s * (1.0f / 768.0f);
    float var = s2 * (1.0f / 768.0f) - mean * mean;
    float rstd = rsqrtf(var + 1e-5f);
    __hip_bfloat16* xo = xn + (size_t)row * 768;
    for (int j = 0; j < 3; j++) {
        int c = tid + j * 256;
        xo[c] = __float2bfloat16((v[j] - mean) * rstd * g[c] + bb[c]);
    }
}

// ---------------- Final split-K reduce: out = x + bias + sum_s P (fp32, to d_out) ----------------
__global__ __launch_bounds__(256) void reduce_out_kernel(
    const __hip_bfloat16* __restrict__ P, int SK,
    const float* __restrict__ bias, const float* __restrict__ x,
    float* __restrict__ out) {
    const size_t MN = (size_t)4096 * 768;
    int row = blockIdx.x, tid = threadIdx.x;
    for (int j = 0; j < 3; j++) {
        int c = tid + j * 256;
        size_t idx = (size_t)row * 768 + c;
        float val = x[idx] + bias[c];
        for (int sk = 0; sk < SK; sk++) val += __bfloat162float(P[(size_t)sk * MN + idx]);
        out[idx] = val;
    }
}

// ---------------- Tiled transpose + cast: fp32 [K,N] -> bf16 [N,K], batched over L ----------------
__global__ __launch_bounds__(256) void transpose_cast_kernel(
    const float* __restrict__ in, __hip_bfloat16* __restrict__ out, int K, int N) {
    __shared__ float tile[32][33];
    size_t off = (size_t)blockIdx.z * K * N;
    in += off; out += off;
    int n0 = blockIdx.x * 32, k0 = blockIdx.y * 32;
    int tx = threadIdx.x & 31, ty = threadIdx.x >> 5;
    for (int i = ty; i < 32; i += 8)
        tile[i][tx] = in[(size_t)(k0 + i) * N + n0 + tx];
    __syncthreads();
    for (int i = ty; i < 32; i += 8)
        out[(size_t)(n0 + i) * K + k0 + tx] = __float2bfloat16(tile[tx][i]);
}

// ---------------- E = exp(sw): fp32 -> bf16 ----------------
__global__ __launch_bounds__(256) void exp_bf16_kernel(
    const float* __restrict__ in, __hip_bfloat16* __restrict__ out, int n4) {
    int i = blockIdx.x * 256 + threadIdx.x;
    if (i >= n4) return;
    float4 v = ((const float4*)in)[i];
    __hip_bfloat16* o = out + (size_t)i * 4;
    o[0] = __float2bfloat16(__expf(v.x)); o[1] = __float2bfloat16(__expf(v.y));
    o[2] = __float2bfloat16(__expf(v.z)); o[3] = __float2bfloat16(__expf(v.w));
}

// ---------------- GEMM: C[M,N] = A[M,K](bf16) @ Bt[N,K](bf16)^T ----------------
// k-major LDS layout: As[quad][row][8] -> fragment reads are 2-way (free) instead of 8-way.
// EPI 0: C bf16.  EPI 1: C bf16 = gelu(acc + bias).  EPI 3: split-K partial bf16 at Cout + z*M*N.
// EPI 4: qkv mode — scale Q columns (col < 768) by 0.125.
template <int EPI>
__global__ __launch_bounds__(256) void gemm_bt_kernel(
    const __hip_bfloat16* __restrict__ A, const __hip_bfloat16* __restrict__ Bt,
    const float* __restrict__ bias,
    void* __restrict__ Cout, int M, int N, int K, int kChunk) {
    __shared__ __hip_bfloat16 As[4 * 128 * 8];
    __shared__ __hip_bfloat16 Bs[4 * 128 * 8];
    int m0 = blockIdx.y * 128, n0 = blockIdx.x * 128;
    int kStart = blockIdx.z * kChunk;
    int tid = threadIdx.x, w = tid >> 6, lane = tid & 63;
    int quad = lane >> 4, l16 = lane & 15;
    int wm = (w & 1) * 64, wn = (w >> 1) * 64;
    f32x4 acc[4][4] = {};
    for (int kt = kStart; kt < kStart + kChunk; kt += 32) {
        __syncthreads();
        for (int c = tid; c < 512; c += 256) {
            int row = c & 127, q = c >> 7;
            __builtin_amdgcn_global_load_lds(
                (const __attribute__((address_space(1))) void*)(A + (size_t)(m0 + row) * K + kt + q * 8),
                (__attribute__((address_space(3))) void*)(&As[c * 8]), 16, 0, 0);
        }
        for (int c = tid; c < 512; c += 256) {
            int row = c & 127, q = c >> 7;
            __builtin_amdgcn_global_load_lds(
                (const __attribute__((address_space(1))) void*)(Bt + (size_t)(n0 + row) * K + kt + q * 8),
                (__attribute__((address_space(3))) void*)(&Bs[c * 8]), 16, 0, 0);
        }
        __syncthreads();
        short8 af[4], bf[4];
        for (int i = 0; i < 4; i++) {
            af[i] = *(const short8*)(As + quad * 1024 + (wm + i * 16 + l16) * 8);
            bf[i] = *(const short8*)(Bs + quad * 1024 + (wn + i * 16 + l16) * 8);
        }
        for (int i = 0; i < 4; i++)
            for (int j = 0; j < 4; j++)
                acc[i][j] = MFMA16(af[i], bf[j], acc[i][j]);
    }
    __hip_bfloat16* Cb = (__hip_bfloat16*)Cout;
    if (EPI == 3) Cb += (size_t)blockIdx.z * M * N;
    float qscale = (EPI == 4 && n0 < 768) ? 0.125f : 1.0f;
    for (int i = 0; i < 4; i++) {
        int rbase = m0 + wm + i * 16 + quad * 4;
        for (int j = 0; j < 4; j++) {
            int col = n0 + wn + j * 16 + l16;
            float bv = (EPI == 1) ? bias[col] : 0.0f;
            for (int r = 0; r < 4; r++) {
                size_t idx = (size_t)(rbase + r) * N + col;
                float v = acc[i][j][r] + bv;
                if (EPI == 1) v = gelu_f(v);
                if (EPI == 4) v *= qscale;
                Cb[idx] = __float2bfloat16(v);
            }
        }
    }
}

// ---------------- Flash attention (no-max softmax; Q pre-scaled; E = exp(sw) multiplicative) ----------------
// grid (8, 12, 16): 128 q-rows/block (4 waves x 32), z = b*4 + part (256 keys each).
// Writes UNNORMALIZED partial O (bf16) + partial l (fp32); merged by attn_merge_kernel.
__global__ __launch_bounds__(256) void attn_kernel(
    const __hip_bfloat16* __restrict__ qkv, const __hip_bfloat16* __restrict__ E,
    __hip_bfloat16* __restrict__ Op, float* __restrict__ lp) {
    int qt = blockIdx.x, h = blockIdx.y;
    int b = blockIdx.z >> 2, part = blockIdx.z & 3;
    int tid = threadIdx.x, w = tid >> 6, lane = tid & 63;
    int quad = lane >> 4, l16 = lane & 15;
    __shared__ __hip_bfloat16 Ks[8 * 64 * 8];  // k-major: [dquad][key][8]
    __shared__ __hip_bfloat16 Vt[64 * 66];     // [d][key], stride 66
    __shared__ __hip_bfloat16 Ps[128 * 66];    // [q][key], stride 66

    short8 qf[2][2];
    for (int mt = 0; mt < 2; mt++) {
        const __hip_bfloat16* qb =
            qkv + (size_t)(b * 1024 + qt * 128 + w * 32 + mt * 16 + l16) * 2304 + h * 64;
        qf[mt][0] = *(const short8*)(qb + quad * 8);
        qf[mt][1] = *(const short8*)(qb + 32 + quad * 8);
    }
    f32x4 o[2][4] = {};
    float lsum[2][4] = {};
    const unsigned int* Pd = (const unsigned int*)Ps;
    const unsigned int* Vd = (const unsigned int*)Vt;

    for (int kt = 0; kt < 256; kt += 64) {
        int key0 = part * 256 + kt;
        __syncthreads();
        // K tile via DMA, k-major: chunk c -> dquad = c>>6, key = c&63
        for (int c = tid; c < 512; c += 256) {
            int key = c & 63, q = c >> 6;
            __builtin_amdgcn_global_load_lds(
                (const __attribute__((address_space(1))) void*)(
                    qkv + (size_t)(b * 1024 + key0 + key) * 2304 + 768 + h * 64 + q * 8),
                (__attribute__((address_space(3))) void*)(&Ks[c * 8]), 16, 0, 0);
        }
        // V tile: float4 load + transposed scalar writes (stride 66)
        for (int c = tid; c < 512; c += 256) {
            int row = c >> 3, ch = c & 7;
            float4 vv = *(const float4*)(qkv + (size_t)(b * 1024 + key0 + row) * 2304 + 1536 + h * 64 + ch * 8);
            const __hip_bfloat16* pv = (const __hip_bfloat16*)&vv;
            #pragma unroll
            for (int j = 0; j < 8; j++) Vt[(ch * 8 + j) * 66 + row] = pv[j];
        }
        __syncthreads();
        // S = Q K^T  (K frags from k-major Ks: 2-way conflicts)
        f32x4 s[2][4];
        for (int nt = 0; nt < 4; nt++) {
            short8 kf0 = *(const short8*)(Ks + quad * 512 + (nt * 16 + l16) * 8);
            short8 kf1 = *(const short8*)(Ks + (quad + 4) * 512 + (nt * 16 + l16) * 8);
            for (int mt = 0; mt < 2; mt++) {
                f32x4 z = {0.f, 0.f, 0.f, 0.f};
                z = MFMA16(qf[mt][0], kf0, z);
                z = MFMA16(qf[mt][1], kf1, z);
                s[mt][nt] = z;
            }
        }
        // P = exp(s) * E  (Q pre-scaled by 0.125; E = exp(sw) precomputed)
        for (int mt = 0; mt < 2; mt++)
            for (int r = 0; r < 4; r++) {
                int qloc = w * 32 + mt * 16 + quad * 4 + r;
                size_t ebase = ((size_t)b << 20) + (size_t)(qt * 128 + qloc) * 1024 + key0;
                float lacc = 0.f;
                #pragma unroll
                for (int nt = 0; nt < 4; nt++) {
                    float e = __bfloat162float(E[ebase + nt * 16 + l16]);
                    float p = __expf(s[mt][nt][r]) * e;
                    Ps[qloc * 66 + nt * 16 + l16] = __float2bfloat16(p);
                    lacc += p;
                }
                lsum[mt][r] += lacc;
            }
        // V B-frags (shared across mt), b32 quads from stride-66 Vt
        short8 vf[4][2];
        for (int dt = 0; dt < 4; dt++)
            for (int kh = 0; kh < 2; kh++) {
                union { unsigned int u[4]; short8 s8; } t;
                int base = (dt * 16 + l16) * 33 + kh * 16 + quad * 4;
                #pragma unroll
                for (int i = 0; i < 4; i++) t.u[i] = Vd[base + i];
                vf[dt][kh] = t.s8;
            }
        // P A-frags + PV
        for (int mt = 0; mt < 2; mt++) {
            int prow = w * 32 + mt * 16 + l16;
            short8 pf[2];
            for (int kh = 0; kh < 2; kh++) {
                union { unsigned int u[4]; short8 s8; } t;
                int base = prow * 33 + kh * 16 + quad * 4;
                #pragma unroll
                for (int i = 0; i < 4; i++) t.u[i] = Pd[base + i];
                pf[kh] = t.s8;
            }
            for (int dt = 0; dt < 4; dt++) {
                o[mt][dt] = MFMA16(pf[0], vf[dt][0], o[mt][dt]);
                o[mt][dt] = MFMA16(pf[1], vf[dt][1], o[mt][dt]);
            }
        }
    }
    for (int mt = 0; mt < 2; mt++)
        for (int r = 0; r < 4; r++) {
            float lv = lsum[mt][r];
            lv += __shfl_xor(lv, 1); lv += __shfl_xor(lv, 2);
            lv += __shfl_xor(lv, 4); lv += __shfl_xor(lv, 8);
            lsum[mt][r] = lv;
        }
    __hip_bfloat16* Oh = Op + (size_t)part * 4096 * 768;
    for (int mt = 0; mt < 2; mt++)
        for (int dt = 0; dt < 4; dt++)
            for (int r = 0; r < 4; r++) {
                int row = b * 1024 + qt * 128 + w * 32 + mt * 16 + quad * 4 + r;
                Oh[(size_t)row * 768 + h * 64 + dt * 16 + l16] = __float2bfloat16(o[mt][dt][r]);
            }
    if (l16 == 0)
        for (int mt = 0; mt < 2; mt++)
            for (int r = 0; r < 4; r++) {
                int q = qt * 128 + w * 32 + mt * 16 + quad * 4 + r;
                lp[part * 49152 + (b * 12 + h) * 1024 + q] = lsum[mt][r];
            }
}

// ---------------- Merge split-KV parts: att = sum(O_p) / sum(l_p) ----------------
__global__ __launch_bounds__(256) void attn_merge_kernel(
    const __hip_bfloat16* __restrict__ Op, const float* __restrict__ lp,
    __hip_bfloat16* __restrict__ att) {
    const size_t MN = (size_t)4096 * 768;
    int row = blockIdx.x, tid = threadIdx.x;
    int b = row >> 10, n = row & 1023;
    for (int j = 0; j < 3; j++) {
        int c = tid + j * 256;
        int h = c >> 6;
        float l = 0.f, v = 0.f;
        size_t idx = (size_t)row * 768 + c;
        for (int p = 0; p < 4; p++) {
            l += lp[p * 49152 + (b * 12 + h) * 1024 + n];
            v += __bfloat162float(Op[p * MN + idx]);
        }
        att[idx] = __float2bfloat16(v / l);
    }
}

extern "C" void kernel_launch(void* const* d_in, const int* in_sizes, int n_in,
                              void* d_out, int out_size, void* d_ws, size_t ws_size,
                              hipStream_t stream) {
    const float* x_in  = (const float*)d_in[0];
    const float* sw_in = (const float*)d_in[1];
    const float* ln1_g = (const float*)d_in[2];
    const float* ln1_b = (const float*)d_in[3];
    const float* w_qkv = (const float*)d_in[4];
    const float* w_out = (const float*)d_in[5];
    const float* b_out = (const float*)d_in[6];
    const float* ln2_g = (const float*)d_in[7];
    const float* ln2_b = (const float*)d_in[8];
    const float* w1    = (const float*)d_in[9];
    const float* b1    = (const float*)d_in[10];
    const float* w2    = (const float*)d_in[11];
    const float* b2    = (const float*)d_in[12];

    char* ws = (char*)d_ws;
    size_t off = 0;
    auto alloc = [&](size_t bytes) -> void* {
        void* p = ws + off;
        off += (bytes + 255) & ~(size_t)255;
        return p;
    };
    float*          x     = (float*)alloc((size_t)4096 * 768 * 4);
    __hip_bfloat16* xn    = (__hip_bfloat16*)alloc((size_t)4096 * 768 * 2);
    __hip_bfloat16* qkv   = (__hip_bfloat16*)alloc((size_t)4096 * 2304 * 2);  // + w2 split-K partials
    __hip_bfloat16* att   = (__hip_bfloat16*)alloc((size_t)4096 * 768 * 2);   // contiguous after qkv
    __hip_bfloat16* hbuf  = (__hip_bfloat16*)alloc((size_t)4096 * 3072 * 2);  // h / attn O-partials / proj partials
    __hip_bfloat16* Ebuf  = (__hip_bfloat16*)alloc((size_t)4 * 1024 * 1024 * 2);
    __hip_bfloat16* wqkvT = (__hip_bfloat16*)alloc((size_t)6 * 2304 * 768 * 2);
    __hip_bfloat16* woutT = (__hip_bfloat16*)alloc((size_t)6 * 768 * 768 * 2);
    __hip_bfloat16* w1T   = (__hip_bfloat16*)alloc((size_t)6 * 3072 * 768 * 2);
    __hip_bfloat16* w2T   = (__hip_bfloat16*)alloc((size_t)6 * 768 * 3072 * 2);
    __hip_bfloat16* Pw2   = qkv;           // 4 x 6.29 MB (qkv + att regions)
    __hip_bfloat16* Opart = hbuf;          // 4 x 6.29 MB (exactly hbuf)
    float*          lpart = (float*)d_out; // 4 x 192 KB scratch in d_out (dead until final reduce)
    __hip_bfloat16* Pproj = hbuf;          // 4 x 6.29 MB (O-partials dead after merge)

    hipMemcpyAsync(x, x_in, (size_t)4096 * 768 * 4, hipMemcpyDeviceToDevice, stream);
    transpose_cast_kernel<<<dim3(2304 / 32, 768 / 32, 6), 256, 0, stream>>>(w_qkv, wqkvT, 768, 2304);
    transpose_cast_kernel<<<dim3(768 / 32, 768 / 32, 6), 256, 0, stream>>>(w_out, woutT, 768, 768);
    transpose_cast_kernel<<<dim3(3072 / 32, 768 / 32, 6), 256, 0, stream>>>(w1, w1T, 768, 3072);
    transpose_cast_kernel<<<dim3(768 / 32, 3072 / 32, 6), 256, 0, stream>>>(w2, w2T, 3072, 768);
    exp_bf16_kernel<<<dim3(4 * 1024 * 1024 / 4 / 256), 256, 0, stream>>>(sw_in, Ebuf, 4 * 1024 * 1024 / 4);

    ln_kernel<<<4096, 256, 0, stream>>>(x, ln1_g, ln1_b, xn);
    for (int l = 0; l < 6; l++) {
        gemm_bt_kernel<4><<<dim3(2304 / 128, 4096 / 128, 1), 256, 0, stream>>>(
            xn, wqkvT + (size_t)l * 2304 * 768, nullptr, qkv, 4096, 2304, 768, 768);
        attn_kernel<<<dim3(8, 12, 16), 256, 0, stream>>>(qkv, Ebuf, Opart, lpart);
        attn_merge_kernel<<<4096, 256, 0, stream>>>(Opart, lpart, att);
        gemm_bt_kernel<3><<<dim3(768 / 128, 4096 / 128, 4), 256, 0, stream>>>(
            att, woutT + (size_t)l * 768 * 768, nullptr, Pproj, 4096, 768, 768, 192);
        reduce_ln_kernel<<<4096, 256, 0, stream>>>(
            Pproj, 4, b_out + l * 768, x, ln2_g + l * 768, ln2_b + l * 768, xn);
        gemm_bt_kernel<1><<<dim3(3072 / 128, 4096 / 128, 1), 256, 0, stream>>>(
            xn, w1T + (size_t)l * 3072 * 768, b1 + l * 3072, hbuf, 4096, 3072, 768, 768);
        gemm_bt_kernel<3><<<dim3(768 / 128, 4096 / 128, 4), 256, 0, stream>>>(
            hbuf, w2T + (size_t)l * 768 * 3072, nullptr, Pw2, 4096, 768, 3072, 768);
        if (l < 5) {
            reduce_ln_kernel<<<4096, 256, 0, stream>>>(
                Pw2, 4, b2 + l * 768, x, ln1_g + (l + 1) * 768, ln1_b + (l + 1) * 768, xn);
        } else {
            reduce_out_kernel<<<4096, 256, 0, stream>>>(Pw2, 4, b2 + l * 768, x, (float*)d_out);
        }
    }
}

// Round 6
// 1433.931 us; speedup vs baseline: 1.2158x; 1.2158x over previous
//
#include <hip/hip_runtime.h>
#include <hip/hip_bf16.h>

typedef __attribute__((ext_vector_type(8))) short short8;   // 8 x bf16
typedef __attribute__((ext_vector_type(4))) float f32x4;

#define MFMA16(a, b, c) __builtin_amdgcn_mfma_f32_16x16x32_bf16(a, b, c, 0, 0, 0)

static __device__ __forceinline__ float gelu_f(float v) {
    return 0.5f * v * (1.0f + erff(v * 0.70710678118654752f));
}

// ---------------- LayerNorm: fp32 x -> bf16 xn (used once, layer-0 ln1) ----------------
__global__ __launch_bounds__(256) void ln_kernel(
    const float* __restrict__ x, const float* __restrict__ g, const float* __restrict__ bb,
    __hip_bfloat16* __restrict__ xn) {
    int row = blockIdx.x;
    const float* xr = x + (size_t)row * 768;
    int tid = threadIdx.x;
    float v0 = xr[tid], v1 = xr[tid + 256], v2 = xr[tid + 512];
    float s = v0 + v1 + v2;
    float s2 = v0 * v0 + v1 * v1 + v2 * v2;
    for (int m = 1; m < 64; m <<= 1) { s += __shfl_xor(s, m); s2 += __shfl_xor(s2, m); }
    __shared__ float ls[4], ls2[4];
    if ((tid & 63) == 0) { ls[tid >> 6] = s; ls2[tid >> 6] = s2; }
    __syncthreads();
    s = ls[0] + ls[1] + ls[2] + ls[3];
    s2 = ls2[0] + ls2[1] + ls2[2] + ls2[3];
    float mean = s * (1.0f / 768.0f);
    float var = s2 * (1.0f / 768.0f) - mean * mean;
    float rstd = rsqrtf(var + 1e-5f);
    __hip_bfloat16* xo = xn + (size_t)row * 768;
    xo[tid]       = __float2bfloat16((v0 - mean) * rstd * g[tid]       + bb[tid]);
    xo[tid + 256] = __float2bfloat16((v1 - mean) * rstd * g[tid + 256] + bb[tid + 256]);
    xo[tid + 512] = __float2bfloat16((v2 - mean) * rstd * g[tid + 512] + bb[tid + 512]);
}

// ---------------- Fused split-K reduce + bias + residual + LayerNorm ----------------
__global__ __launch_bounds__(256) void reduce_ln_kernel(
    const __hip_bfloat16* __restrict__ P, int SK,
    const float* __restrict__ bias, float* __restrict__ x,
    const float* __restrict__ g, const float* __restrict__ bb,
    __hip_bfloat16* __restrict__ xn) {
    const size_t MN = (size_t)4096 * 768;
    int row = blockIdx.x, tid = threadIdx.x;
    float v[3];
    float s = 0.f, s2 = 0.f;
    for (int j = 0; j < 3; j++) {
        int c = tid + j * 256;
        size_t idx = (size_t)row * 768 + c;
        float val = x[idx] + bias[c];
        for (int sk = 0; sk < SK; sk++) val += __bfloat162float(P[(size_t)sk * MN + idx]);
        x[idx] = val;
        v[j] = val;
        s += val; s2 += val * val;
    }
    for (int m = 1; m < 64; m <<= 1) { s += __shfl_xor(s, m); s2 += __shfl_xor(s2, m); }
    __shared__ float ls[4], ls2[4];
    if ((tid & 63) == 0) { ls[tid >> 6] = s; ls2[tid >> 6] = s2; }
    __syncthreads();
    s = ls[0] + ls[1] + ls[2] + ls[3];
    s2 = ls2[0] + ls2[1] + ls2[2] + ls2[3];
    float mean = s * (1.0f / 768.0f);
    float var = s2 * (1.0f / 768.0f) - mean * mean;
    float rstd = rsqrtf(var + 1e-5f);
    __hip_bfloat16* xo = xn + (size_t)row * 768;
    for (int j = 0; j < 3; j++) {
        int c = tid + j * 256;
        xo[c] = __float2bfloat16((v[j] - mean) * rstd * g[c] + bb[c]);
    }
}

// ---------------- Final split-K reduce: out = x + bias + sum_s P (fp32, to d_out) ----------------
__global__ __launch_bounds__(256) void reduce_out_kernel(
    const __hip_bfloat16* __restrict__ P, int SK,
    const float* __restrict__ bias, const float* __restrict__ x,
    float* __restrict__ out) {
    const size_t MN = (size_t)4096 * 768;
    int row = blockIdx.x, tid = threadIdx.x;
    for (int j = 0; j < 3; j++) {
        int c = tid + j * 256;
        size_t idx = (size_t)row * 768 + c;
        float val = x[idx] + bias[c];
        for (int sk = 0; sk < SK; sk++) val += __bfloat162float(P[(size_t)sk * MN + idx]);
        out[idx] = val;
    }
}

// ---------------- Tiled transpose + cast: fp32 [K,N] -> bf16 [N,K], batched over L ----------------
__global__ __launch_bounds__(256) void transpose_cast_kernel(
    const float* __restrict__ in, __hip_bfloat16* __restrict__ out, int K, int N) {
    __shared__ float tile[32][33];
    size_t off = (size_t)blockIdx.z * K * N;
    in += off; out += off;
    int n0 = blockIdx.x * 32, k0 = blockIdx.y * 32;
    int tx = threadIdx.x & 31, ty = threadIdx.x >> 5;
    for (int i = ty; i < 32; i += 8)
        tile[i][tx] = in[(size_t)(k0 + i) * N + n0 + tx];
    __syncthreads();
    for (int i = ty; i < 32; i += 8)
        out[(size_t)(n0 + i) * K + k0 + tx] = __float2bfloat16(tile[tx][i]);
}

// ---------------- E = exp(sw): fp32 -> bf16 ----------------
__global__ __launch_bounds__(256) void exp_bf16_kernel(
    const float* __restrict__ in, __hip_bfloat16* __restrict__ out, int n4) {
    int i = blockIdx.x * 256 + threadIdx.x;
    if (i >= n4) return;
    float4 v = ((const float4*)in)[i];
    __hip_bfloat16* o = out + (size_t)i * 4;
    o[0] = __float2bfloat16(__expf(v.x)); o[1] = __float2bfloat16(__expf(v.y));
    o[2] = __float2bfloat16(__expf(v.z)); o[3] = __float2bfloat16(__expf(v.w));
}

// ---------------- GEMM: C[M,N] = A[M,K](bf16) @ Bt[N,K](bf16)^T ----------------
// XOR-swizzled LDS: chunk c holds (row = c>>2, q = (c&3)^((c>>3)&3)).
// DMA stays coalesced (4 lanes = one row's 64 B); fragment reads are phase-optimal.
// EPI 0: C bf16.  EPI 1: C bf16 = gelu(acc + bias).  EPI 3: split-K partial bf16 at Cout + z*M*N.
// EPI 4: qkv mode — scale Q columns (col < 768) by 0.125.
template <int EPI>
__global__ __launch_bounds__(256) void gemm_bt_kernel(
    const __hip_bfloat16* __restrict__ A, const __hip_bfloat16* __restrict__ Bt,
    const float* __restrict__ bias,
    void* __restrict__ Cout, int M, int N, int K, int kChunk) {
    __shared__ __hip_bfloat16 As[128 * 32];
    __shared__ __hip_bfloat16 Bs[128 * 32];
    int m0 = blockIdx.y * 128, n0 = blockIdx.x * 128;
    int kStart = blockIdx.z * kChunk;
    int tid = threadIdx.x, w = tid >> 6, lane = tid & 63;
    int quad = lane >> 4, l16 = lane & 15;
    int wm = (w & 1) * 64, wn = (w >> 1) * 64;
    int xq = (quad ^ (l16 >> 1)) & 3;   // swizzled k-quad for fragment reads
    f32x4 acc[4][4] = {};
    for (int kt = kStart; kt < kStart + kChunk; kt += 32) {
        __syncthreads();
        for (int c = tid; c < 512; c += 256) {
            int row = c >> 2, q = (c ^ (c >> 3)) & 3;
            __builtin_amdgcn_global_load_lds(
                (const __attribute__((address_space(1))) void*)(A + (size_t)(m0 + row) * K + kt + q * 8),
                (__attribute__((address_space(3))) void*)(&As[c * 8]), 16, 0, 0);
        }
        for (int c = tid; c < 512; c += 256) {
            int row = c >> 2, q = (c ^ (c >> 3)) & 3;
            __builtin_amdgcn_global_load_lds(
                (const __attribute__((address_space(1))) void*)(Bt + (size_t)(n0 + row) * K + kt + q * 8),
                (__attribute__((address_space(3))) void*)(&Bs[c * 8]), 16, 0, 0);
        }
        __syncthreads();
        short8 af[4], bf[4];
        for (int i = 0; i < 4; i++) {
            af[i] = *(const short8*)(As + (wm + i * 16 + l16) * 32 + xq * 8);
            bf[i] = *(const short8*)(Bs + (wn + i * 16 + l16) * 32 + xq * 8);
        }
        for (int i = 0; i < 4; i++)
            for (int j = 0; j < 4; j++)
                acc[i][j] = MFMA16(af[i], bf[j], acc[i][j]);
    }
    __hip_bfloat16* Cb = (__hip_bfloat16*)Cout;
    if (EPI == 3) Cb += (size_t)blockIdx.z * M * N;
    float qscale = (EPI == 4 && n0 < 768) ? 0.125f : 1.0f;
    for (int i = 0; i < 4; i++) {
        int rbase = m0 + wm + i * 16 + quad * 4;
        for (int j = 0; j < 4; j++) {
            int col = n0 + wn + j * 16 + l16;
            float bv = (EPI == 1) ? bias[col] : 0.0f;
            for (int r = 0; r < 4; r++) {
                size_t idx = (size_t)(rbase + r) * N + col;
                float v = acc[i][j][r] + bv;
                if (EPI == 1) v = gelu_f(v);
                if (EPI == 4) v *= qscale;
                Cb[idx] = __float2bfloat16(v);
            }
        }
    }
}

// ---------------- Flash attention (no-max softmax; Q pre-scaled; E = exp(sw) multiplicative) ----------------
// grid (8, 12, 16): 128 q-rows/block (4 waves x 32), z = b*4 + part (256 keys each).
// K tile: XOR-swizzled DMA (chunk c -> key = c>>3, q = (c^key)&7): coalesced 128 B/key + clean reads.
__global__ __launch_bounds__(256) void attn_kernel(
    const __hip_bfloat16* __restrict__ qkv, const __hip_bfloat16* __restrict__ E,
    __hip_bfloat16* __restrict__ Op, float* __restrict__ lp) {
    int qt = blockIdx.x, h = blockIdx.y;
    int b = blockIdx.z >> 2, part = blockIdx.z & 3;
    int tid = threadIdx.x, w = tid >> 6, lane = tid & 63;
    int quad = lane >> 4, l16 = lane & 15;
    __shared__ __hip_bfloat16 Ks[64 * 64];   // swizzled [key][8 chunks of 8]
    __shared__ __hip_bfloat16 Vt[64 * 66];   // [d][key], stride 66
    __shared__ __hip_bfloat16 Ps[128 * 66];  // [q][key], stride 66

    short8 qf[2][2];
    for (int mt = 0; mt < 2; mt++) {
        const __hip_bfloat16* qb =
            qkv + (size_t)(b * 1024 + qt * 128 + w * 32 + mt * 16 + l16) * 2304 + h * 64;
        qf[mt][0] = *(const short8*)(qb + quad * 8);
        qf[mt][1] = *(const short8*)(qb + 32 + quad * 8);
    }
    f32x4 o[2][4] = {};
    float lsum[2][4] = {};
    const unsigned int* Pd = (const unsigned int*)Ps;
    const unsigned int* Vd = (const unsigned int*)Vt;

    for (int kt = 0; kt < 256; kt += 64) {
        int key0 = part * 256 + kt;
        __syncthreads();
        // K tile via swizzled DMA
        for (int c = tid; c < 512; c += 256) {
            int key = c >> 3, q = (c ^ key) & 7;
            __builtin_amdgcn_global_load_lds(
                (const __attribute__((address_space(1))) void*)(
                    qkv + (size_t)(b * 1024 + key0 + key) * 2304 + 768 + h * 64 + q * 8),
                (__attribute__((address_space(3))) void*)(&Ks[c * 8]), 16, 0, 0);
        }
        // V tile: float4 load + transposed scalar writes (stride 66)
        for (int c = tid; c < 512; c += 256) {
            int row = c >> 3, ch = c & 7;
            float4 vv = *(const float4*)(qkv + (size_t)(b * 1024 + key0 + row) * 2304 + 1536 + h * 64 + ch * 8);
            const __hip_bfloat16* pv = (const __hip_bfloat16*)&vv;
            #pragma unroll
            for (int j = 0; j < 8; j++) Vt[(ch * 8 + j) * 66 + row] = pv[j];
        }
        __syncthreads();
        // S = Q K^T  (swizzled K frag reads)
        f32x4 s[2][4];
        for (int nt = 0; nt < 4; nt++) {
            int kk = nt * 16 + l16;
            int x0 = (quad ^ kk) & 7;
            short8 kf0 = *(const short8*)(Ks + kk * 64 + x0 * 8);
            short8 kf1 = *(const short8*)(Ks + kk * 64 + (x0 ^ 4) * 8);
            for (int mt = 0; mt < 2; mt++) {
                f32x4 z = {0.f, 0.f, 0.f, 0.f};
                z = MFMA16(qf[mt][0], kf0, z);
                z = MFMA16(qf[mt][1], kf1, z);
                s[mt][nt] = z;
            }
        }
        // P = exp(s) * E  (Q pre-scaled by 0.125; E = exp(sw) precomputed)
        for (int mt = 0; mt < 2; mt++)
            for (int r = 0; r < 4; r++) {
                int qloc = w * 32 + mt * 16 + quad * 4 + r;
                size_t ebase = ((size_t)b << 20) + (size_t)(qt * 128 + qloc) * 1024 + key0;
                float lacc = 0.f;
                #pragma unroll
                for (int nt = 0; nt < 4; nt++) {
                    float e = __bfloat162float(E[ebase + nt * 16 + l16]);
                    float p = __expf(s[mt][nt][r]) * e;
                    Ps[qloc * 66 + nt * 16 + l16] = __float2bfloat16(p);
                    lacc += p;
                }
                lsum[mt][r] += lacc;
            }
        // V B-frags (shared across mt), b32 quads from stride-66 Vt
        short8 vf[4][2];
        for (int dt = 0; dt < 4; dt++)
            for (int kh = 0; kh < 2; kh++) {
                union { unsigned int u[4]; short8 s8; } t;
                int base = (dt * 16 + l16) * 33 + kh * 16 + quad * 4;
                #pragma unroll
                for (int i = 0; i < 4; i++) t.u[i] = Vd[base + i];
                vf[dt][kh] = t.s8;
            }
        // P A-frags + PV
        for (int mt = 0; mt < 2; mt++) {
            int prow = w * 32 + mt * 16 + l16;
            short8 pf[2];
            for (int kh = 0; kh < 2; kh++) {
                union { unsigned int u[4]; short8 s8; } t;
                int base = prow * 33 + kh * 16 + quad * 4;
                #pragma unroll
                for (int i = 0; i < 4; i++) t.u[i] = Pd[base + i];
                pf[kh] = t.s8;
            }
            for (int dt = 0; dt < 4; dt++) {
                o[mt][dt] = MFMA16(pf[0], vf[dt][0], o[mt][dt]);
                o[mt][dt] = MFMA16(pf[1], vf[dt][1], o[mt][dt]);
            }
        }
    }
    for (int mt = 0; mt < 2; mt++)
        for (int r = 0; r < 4; r++) {
            float lv = lsum[mt][r];
            lv += __shfl_xor(lv, 1); lv += __shfl_xor(lv, 2);
            lv += __shfl_xor(lv, 4); lv += __shfl_xor(lv, 8);
            lsum[mt][r] = lv;
        }
    __hip_bfloat16* Oh = Op + (size_t)part * 4096 * 768;
    for (int mt = 0; mt < 2; mt++)
        for (int dt = 0; dt < 4; dt++)
            for (int r = 0; r < 4; r++) {
                int row = b * 1024 + qt * 128 + w * 32 + mt * 16 + quad * 4 + r;
                Oh[(size_t)row * 768 + h * 64 + dt * 16 + l16] = __float2bfloat16(o[mt][dt][r]);
            }
    if (l16 == 0)
        for (int mt = 0; mt < 2; mt++)
            for (int r = 0; r < 4; r++) {
                int q = qt * 128 + w * 32 + mt * 16 + quad * 4 + r;
                lp[part * 49152 + (b * 12 + h) * 1024 + q] = lsum[mt][r];
            }
}

// ---------------- Merge split-KV parts: att = sum(O_p) / sum(l_p) ----------------
__global__ __launch_bounds__(256) void attn_merge_kernel(
    const __hip_bfloat16* __restrict__ Op, const float* __restrict__ lp,
    __hip_bfloat16* __restrict__ att) {
    const size_t MN = (size_t)4096 * 768;
    int row = blockIdx.x, tid = threadIdx.x;
    int b = row >> 10, n = row & 1023;
    for (int j = 0; j < 3; j++) {
        int c = tid + j * 256;
        int h = c >> 6;
        float l = 0.f, v = 0.f;
        size_t idx = (size_t)row * 768 + c;
        for (int p = 0; p < 4; p++) {
            l += lp[p * 49152 + (b * 12 + h) * 1024 + n];
            v += __bfloat162float(Op[p * MN + idx]);
        }
        att[idx] = __float2bfloat16(v / l);
    }
}

extern "C" void kernel_launch(void* const* d_in, const int* in_sizes, int n_in,
                              void* d_out, int out_size, void* d_ws, size_t ws_size,
                              hipStream_t stream) {
    const float* x_in  = (const float*)d_in[0];
    const float* sw_in = (const float*)d_in[1];
    const float* ln1_g = (const float*)d_in[2];
    const float* ln1_b = (const float*)d_in[3];
    const float* w_qkv = (const float*)d_in[4];
    const float* w_out = (const float*)d_in[5];
    const float* b_out = (const float*)d_in[6];
    const float* ln2_g = (const float*)d_in[7];
    const float* ln2_b = (const float*)d_in[8];
    const float* w1    = (const float*)d_in[9];
    const float* b1    = (const float*)d_in[10];
    const float* w2    = (const float*)d_in[11];
    const float* b2    = (const float*)d_in[12];

    char* ws = (char*)d_ws;
    size_t off = 0;
    auto alloc = [&](size_t bytes) -> void* {
        void* p = ws + off;
        off += (bytes + 255) & ~(size_t)255;
        return p;
    };
    float*          x     = (float*)alloc((size_t)4096 * 768 * 4);
    __hip_bfloat16* xn    = (__hip_bfloat16*)alloc((size_t)4096 * 768 * 2);
    __hip_bfloat16* qkv   = (__hip_bfloat16*)alloc((size_t)4096 * 2304 * 2);  // + w2 split-K partials
    __hip_bfloat16* att   = (__hip_bfloat16*)alloc((size_t)4096 * 768 * 2);   // contiguous after qkv
    __hip_bfloat16* hbuf  = (__hip_bfloat16*)alloc((size_t)4096 * 3072 * 2);  // h / attn O-partials / proj partials
    __hip_bfloat16* Ebuf  = (__hip_bfloat16*)alloc((size_t)4 * 1024 * 1024 * 2);
    float*          lpart = (float*)alloc((size_t)4 * 49152 * 4);             // attn l-partials (ws, NOT d_out)
    __hip_bfloat16* wqkvT = (__hip_bfloat16*)alloc((size_t)6 * 2304 * 768 * 2);
    __hip_bfloat16* woutT = (__hip_bfloat16*)alloc((size_t)6 * 768 * 768 * 2);
    __hip_bfloat16* w1T   = (__hip_bfloat16*)alloc((size_t)6 * 3072 * 768 * 2);
    __hip_bfloat16* w2T   = (__hip_bfloat16*)alloc((size_t)6 * 768 * 3072 * 2);
    __hip_bfloat16* Pw2   = qkv;   // 4 x 6.29 MB (qkv + att regions)
    __hip_bfloat16* Opart = hbuf;  // 4 x 6.29 MB (exactly hbuf)
    __hip_bfloat16* Pproj = hbuf;  // 4 x 6.29 MB (O-partials dead after merge)

    hipMemcpyAsync(x, x_in, (size_t)4096 * 768 * 4, hipMemcpyDeviceToDevice, stream);
    transpose_cast_kernel<<<dim3(2304 / 32, 768 / 32, 6), 256, 0, stream>>>(w_qkv, wqkvT, 768, 2304);
    transpose_cast_kernel<<<dim3(768 / 32, 768 / 32, 6), 256, 0, stream>>>(w_out, woutT, 768, 768);
    transpose_cast_kernel<<<dim3(3072 / 32, 768 / 32, 6), 256, 0, stream>>>(w1, w1T, 768, 3072);
    transpose_cast_kernel<<<dim3(768 / 32, 3072 / 32, 6), 256, 0, stream>>>(w2, w2T, 3072, 768);
    exp_bf16_kernel<<<dim3(4 * 1024 * 1024 / 4 / 256), 256, 0, stream>>>(sw_in, Ebuf, 4 * 1024 * 1024 / 4);

    ln_kernel<<<4096, 256, 0, stream>>>(x, ln1_g, ln1_b, xn);
    for (int l = 0; l < 6; l++) {
        gemm_bt_kernel<4><<<dim3(2304 / 128, 4096 / 128, 1), 256, 0, stream>>>(
            xn, wqkvT + (size_t)l * 2304 * 768, nullptr, qkv, 4096, 2304, 768, 768);
        attn_kernel<<<dim3(8, 12, 16), 256, 0, stream>>>(qkv, Ebuf, Opart, lpart);
        attn_merge_kernel<<<4096, 256, 0, stream>>>(Opart, lpart, att);
        gemm_bt_kernel<3><<<dim3(768 / 128, 4096 / 128, 4), 256, 0, stream>>>(
            att, woutT + (size_t)l * 768 * 768, nullptr, Pproj, 4096, 768, 768, 192);
        reduce_ln_kernel<<<4096, 256, 0, stream>>>(
            Pproj, 4, b_out + l * 768, x, ln2_g + l * 768, ln2_b + l * 768, xn);
        gemm_bt_kernel<1><<<dim3(3072 / 128, 4096 / 128, 1), 256, 0, stream>>>(
            xn, w1T + (size_t)l * 3072 * 768, b1 + l * 3072, hbuf, 4096, 3072, 768, 768);
        gemm_bt_kernel<3><<<dim3(768 / 128, 4096 / 128, 4), 256, 0, stream>>>(
            hbuf, w2T + (size_t)l * 768 * 3072, nullptr, Pw2, 4096, 768, 3072, 768);
        if (l < 5) {
            reduce_ln_kernel<<<4096, 256, 0, stream>>>(
                Pw2, 4, b2 + l * 768, x, ln1_g + (l + 1) * 768, ln1_b + (l + 1) * 768, xn);
        } else {
            reduce_out_kernel<<<4096, 256, 0, stream>>>(Pw2, 4, b2 + l * 768, x, (float*)d_out);
        }
    }
}